// Round 1
// baseline (573.802 us; speedup 1.0000x reference)
//
#include <hip/hip_runtime.h>
#include <hip/hip_bf16.h>

// Problem constants
#define N_IN  2048
#define N_HID 4096
#define N_OUT 1024
#define N_TOT 7168
#define BATCH 4096
#define LDA2  (N_IN + N_HID)   // 6144: [x | H] activation buffer leading dim

typedef __attribute__((ext_vector_type(8))) short short8;
typedef __attribute__((ext_vector_type(4))) float f32x4;

static __device__ __forceinline__ unsigned short f2bf(float f) {
  __hip_bfloat16 h = __float2bfloat16(f);
  return __builtin_bit_cast(unsigned short, h);
}

// ---------------------------------------------------------------------------
// Convert x (BATCH x N_IN fp32) -> bf16 into A2[:, 0:2048] (row stride 6144)
// ---------------------------------------------------------------------------
__global__ void conv_x_kernel(const float* __restrict__ x,
                              unsigned short* __restrict__ A2) {
  int idx = blockIdx.x * 256 + threadIdx.x;     // BATCH*N_IN/4 threads
  int row = idx >> 9;                           // N_IN/4 = 512 groups per row
  int col = (idx & 511) << 2;
  const float4 v = *(const float4*)(x + (size_t)row * N_IN + col);
  ushort4 o;
  o.x = f2bf(v.x); o.y = f2bf(v.y); o.z = f2bf(v.z); o.w = f2bf(v.w);
  *(ushort4*)(A2 + (size_t)row * LDA2 + col) = o;
}

// ---------------------------------------------------------------------------
// Transpose-convert: dst[n][k] = (bf16)src[k][n]
// src: SK x SN fp32 region with row stride lds_; dst: SN x SK bf16, stride ldd
// 32x32 tiles, 256 threads.
// ---------------------------------------------------------------------------
__global__ void conv_t_kernel(const float* __restrict__ src, int lds_,
                              unsigned short* __restrict__ dst, int ldd,
                              int SK, int SN) {
  __shared__ float tile[32][33];
  const int t = threadIdx.x;
  const int k0 = blockIdx.y << 5, n0 = blockIdx.x << 5;
  const int r = t >> 3, c = (t & 7) << 2;
  const float4 v = *(const float4*)(src + (size_t)(k0 + r) * lds_ + n0 + c);
  tile[r][c] = v.x; tile[r][c + 1] = v.y; tile[r][c + 2] = v.z; tile[r][c + 3] = v.w;
  __syncthreads();
  ushort4 o;
  o.x = f2bf(tile[c][r]);
  o.y = f2bf(tile[c + 1][r]);
  o.z = f2bf(tile[c + 2][r]);
  o.w = f2bf(tile[c + 3][r]);
  *(ushort4*)(dst + (size_t)(n0 + r) * ldd + k0 + c) = o;
}

// ---------------------------------------------------------------------------
// GEMM: C = A @ B, A row-major (M x K bf16, stride lda), Bt row-major
// (N x K bf16, stride ldb) i.e. B transposed. 128x128 tile, BK=64,
// 4 waves x (64x64), 16x16x32 bf16 MFMA, global_load_lds width-16 staging.
// RELU_BF16: relu + bf16 store (stride ldc); else fp32 store.
// M, N, K all multiples of 128/128/64 for this problem — no bounds checks.
// ---------------------------------------------------------------------------
template <bool RELU_BF16>
__global__ __launch_bounds__(256)
void gemm_bt(const unsigned short* __restrict__ A, int lda,
             const unsigned short* __restrict__ Bt, int ldb,
             void* __restrict__ Cv, int ldc, int K) {
  __shared__ __align__(16) unsigned short As[128 * 64];
  __shared__ __align__(16) unsigned short Bs[128 * 64];

  const int tid  = threadIdx.x;
  const int lane = tid & 63;
  const int wave = tid >> 6;
  const int wy = wave >> 1, wx = wave & 1;
  const int lm = lane & 15, quad = lane >> 4;
  const int bm = blockIdx.y, bn = blockIdx.x;

  // staging: chunk gi = wave*256 + i*64 + lane ; row = gi>>3, col = (gi&7)*8
  const int gi   = wave * 256 + lane;
  const int grow = gi >> 3;
  const int gcol = (gi & 7) << 3;

  const unsigned short* Ag = A  + (size_t)(bm * 128 + grow) * lda + gcol;
  const unsigned short* Bg = Bt + (size_t)(bn * 128 + grow) * ldb + gcol;
  unsigned short* Asl = As + wave * 2048;   // (wave*4)*512
  unsigned short* Bsl = Bs + wave * 2048;

  f32x4 acc[4][4];
#pragma unroll
  for (int i = 0; i < 4; ++i)
#pragma unroll
    for (int j = 0; j < 4; ++j)
      acc[i][j] = (f32x4){0.f, 0.f, 0.f, 0.f};

  for (int ko = 0; ko < K; ko += 64) {
    __syncthreads();   // previous iter's compute done before overwrite
#pragma unroll
    for (int i = 0; i < 4; ++i) {
      __builtin_amdgcn_global_load_lds(
          (const __attribute__((address_space(1))) void*)(Ag + (size_t)(8 * i) * lda + ko),
          (__attribute__((address_space(3))) void*)(Asl + i * 512), 16, 0, 0);
      __builtin_amdgcn_global_load_lds(
          (const __attribute__((address_space(1))) void*)(Bg + (size_t)(8 * i) * ldb + ko),
          (__attribute__((address_space(3))) void*)(Bsl + i * 512), 16, 0, 0);
    }
    __syncthreads();   // emits s_waitcnt vmcnt(0) before s_barrier

#pragma unroll
    for (int kk = 0; kk < 2; ++kk) {
      short8 av[4], bv[4];
#pragma unroll
      for (int mt = 0; mt < 4; ++mt)
        av[mt] = *(const short8*)(As + (wy * 64 + mt * 16 + lm) * 64 + kk * 32 + quad * 8);
#pragma unroll
      for (int nt = 0; nt < 4; ++nt)
        bv[nt] = *(const short8*)(Bs + (wx * 64 + nt * 16 + lm) * 64 + kk * 32 + quad * 8);
#pragma unroll
      for (int mt = 0; mt < 4; ++mt)
#pragma unroll
        for (int nt = 0; nt < 4; ++nt)
          acc[mt][nt] = __builtin_amdgcn_mfma_f32_16x16x32_bf16(
              av[mt], bv[nt], acc[mt][nt], 0, 0, 0);
    }
  }

  // epilogue: C/D layout col = lane&15, row = quad*4 + reg  [m89-verified]
  if (RELU_BF16) {
    unsigned short* C = (unsigned short*)Cv;
#pragma unroll
    for (int mt = 0; mt < 4; ++mt) {
      const int row0 = bm * 128 + wy * 64 + mt * 16 + quad * 4;
#pragma unroll
      for (int nt = 0; nt < 4; ++nt) {
        const int col = bn * 128 + wx * 64 + nt * 16 + lm;
#pragma unroll
        for (int r = 0; r < 4; ++r) {
          float v = acc[mt][nt][r];
          v = v > 0.f ? v : 0.f;
          C[(size_t)(row0 + r) * ldc + col] = f2bf(v);
        }
      }
    }
  } else {
    float* C = (float*)Cv;
#pragma unroll
    for (int mt = 0; mt < 4; ++mt) {
      const int row0 = bm * 128 + wy * 64 + mt * 16 + quad * 4;
#pragma unroll
      for (int nt = 0; nt < 4; ++nt) {
        const int col = bn * 128 + wx * 64 + nt * 16 + lm;
#pragma unroll
        for (int r = 0; r < 4; ++r)
          C[(size_t)(row0 + r) * ldc + col] = acc[mt][nt][r];
      }
    }
  }
}

// ---------------------------------------------------------------------------
// kernel_launch
// inputs: d_in[0]=x (4096x2048 f32), d_in[1]=weights (7168x7168 f32),
//         d_in[2]=structure_mask (unused — mask is 1 over every slice we read)
// out: 4096x1024 f32
// ws layout: A2 bf16 4096x6144 | Bt1 bf16 4096x2048 | Bt2 bf16 1024x6144
// ---------------------------------------------------------------------------
extern "C" void kernel_launch(void* const* d_in, const int* in_sizes, int n_in,
                              void* d_out, int out_size, void* d_ws, size_t ws_size,
                              hipStream_t stream) {
  const float* x = (const float*)d_in[0];
  const float* W = (const float*)d_in[1];

  char* ws = (char*)d_ws;
  const size_t A2_BYTES  = (size_t)BATCH * LDA2 * 2;       // 50,331,648
  const size_t BT1_BYTES = (size_t)N_HID * N_IN * 2;       // 16,777,216
  unsigned short* A2  = (unsigned short*)ws;
  unsigned short* Bt1 = (unsigned short*)(ws + A2_BYTES);
  unsigned short* Bt2 = (unsigned short*)(ws + A2_BYTES + BT1_BYTES);

  // 1) x -> bf16 into A2[:, 0:2048]
  conv_x_kernel<<<(BATCH * N_IN / 4) / 256, 256, 0, stream>>>(x, A2);

  // 2) Bt1[n][k] = W[k][2048+n], k<2048, n<4096  (W1^T)
  conv_t_kernel<<<dim3(N_HID / 32, N_IN / 32), 256, 0, stream>>>(
      W + N_IN, N_TOT, Bt1, N_IN, N_IN, N_HID);

  // 3) Bt2[n][k] = W[k][6144+n], k<6144, n<1024  ([W2;W3]^T)
  conv_t_kernel<<<dim3(N_OUT / 32, LDA2 / 32), 256, 0, stream>>>(
      W + N_IN + N_HID, N_TOT, Bt2, LDA2, LDA2, N_OUT);

  // 4) H = relu(x @ W1) -> bf16 into A2[:, 2048:6144]
  gemm_bt<true><<<dim3(N_HID / 128, BATCH / 128), 256, 0, stream>>>(
      A2, LDA2, Bt1, N_IN, A2 + N_IN, LDA2, N_IN);

  // 5) out = [x,H] @ [W2;W3] -> fp32 d_out
  gemm_bt<false><<<dim3(N_OUT / 128, BATCH / 128), 256, 0, stream>>>(
      A2, LDA2, Bt2, LDA2, d_out, N_OUT, LDA2);
}

// Round 2
// 518.001 us; speedup vs baseline: 1.1077x; 1.1077x over previous
//
#include <hip/hip_runtime.h>
#include <hip/hip_bf16.h>

// Problem constants
#define N_IN  2048
#define N_HID 4096
#define N_OUT 1024
#define N_TOT 7168
#define BATCH 4096
#define LDA2  (N_IN + N_HID)   // 6144: [x | H] activation buffer leading dim

typedef __attribute__((ext_vector_type(8))) short short8;
typedef __attribute__((ext_vector_type(4))) float f32x4;

static __device__ __forceinline__ unsigned short f2bf(float f) {
  __hip_bfloat16 h = __float2bfloat16(f);
  return __builtin_bit_cast(unsigned short, h);
}

// ---------------------------------------------------------------------------
// Convert x (BATCH x N_IN fp32) -> bf16 into A2[:, 0:2048] (row stride 6144)
// ---------------------------------------------------------------------------
__global__ void conv_x_kernel(const float* __restrict__ x,
                              unsigned short* __restrict__ A2) {
  int idx = blockIdx.x * 256 + threadIdx.x;     // BATCH*N_IN/4 threads
  int row = idx >> 9;                           // N_IN/4 = 512 groups per row
  int col = (idx & 511) << 2;
  const float4 v = *(const float4*)(x + (size_t)row * N_IN + col);
  ushort4 o;
  o.x = f2bf(v.x); o.y = f2bf(v.y); o.z = f2bf(v.z); o.w = f2bf(v.w);
  *(ushort4*)(A2 + (size_t)row * LDA2 + col) = o;
}

// ---------------------------------------------------------------------------
// Transpose-convert: dst[n][k] = (bf16)src[k][n]
// src: SK x SN fp32 region with row stride lds_; dst: SN x SK bf16, stride ldd
// 32x32 tiles, 256 threads.
// ---------------------------------------------------------------------------
__global__ void conv_t_kernel(const float* __restrict__ src, int lds_,
                              unsigned short* __restrict__ dst, int ldd,
                              int SK, int SN) {
  __shared__ float tile[32][33];
  const int t = threadIdx.x;
  const int k0 = blockIdx.y << 5, n0 = blockIdx.x << 5;
  const int r = t >> 3, c = (t & 7) << 2;
  const float4 v = *(const float4*)(src + (size_t)(k0 + r) * lds_ + n0 + c);
  tile[r][c] = v.x; tile[r][c + 1] = v.y; tile[r][c + 2] = v.z; tile[r][c + 3] = v.w;
  __syncthreads();
  ushort4 o;
  o.x = f2bf(tile[c][r]);
  o.y = f2bf(tile[c + 1][r]);
  o.z = f2bf(tile[c + 2][r]);
  o.w = f2bf(tile[c + 3][r]);
  *(ushort4*)(dst + (size_t)(n0 + r) * ldd + k0 + c) = o;
}

// ---------------------------------------------------------------------------
// GEMM: C = A @ B, A row-major (M x K bf16, stride lda), Bt row-major
// (N x K bf16, stride ldb). 128x128 tile, BK=64, 4 waves x (64x64),
// 16x16x32 bf16 MFMA, global_load_lds width-16 staging.
//
// LDS layout is XOR-swizzled to kill the 16-way bank conflicts of a plain
// 128B-row layout: physical 16B-chunk p of row r holds logical chunk
// p ^ (r&7). The staging side implements this by permuting the PER-LANE
// global source column (global_load_lds dest is fixed lane-ordered);
// readers XOR the chunk index with (row&7). Fragment reads are then 2-way
// (free, m136) instead of 16-way (5.7x).
//
// WMODE: 0 = fp32 store, 1 = relu + bf16 store, 2 = fp32 atomicAdd (split-K;
// with exactly 2 contributions per element this is bit-deterministic).
// blockIdx.z * Klen gives the K offset.
// ---------------------------------------------------------------------------
template <int WMODE>
__global__ __launch_bounds__(256)
void gemm_bt(const unsigned short* __restrict__ A, int lda,
             const unsigned short* __restrict__ Bt, int ldb,
             void* __restrict__ Cv, int ldc, int Klen) {
  __shared__ __align__(16) unsigned short As[128 * 64];
  __shared__ __align__(16) unsigned short Bs[128 * 64];

  const int tid  = threadIdx.x;
  const int lane = tid & 63;
  const int wave = tid >> 6;
  const int wy = wave >> 1, wx = wave & 1;
  const int lm = lane & 15, quad = lane >> 4;
  const int bm = blockIdx.y, bn = blockIdx.x;
  const int ko0 = blockIdx.z * Klen;

  // staging: LDS chunk index = wave*256 + i*64 + lane -> row=idx>>3, phys
  // chunk=lane&7. Source column is swizzled: logical chunk = (lane&7)^(lane>>3)
  // (row&7 == lane>>3 for every i since i contributes multiples of 8 rows).
  const int grow = (wave << 5) + (lane >> 3);
  const int gcol = ((lane & 7) ^ (lane >> 3)) << 3;

  const unsigned short* Ag = A  + (size_t)(bm * 128 + grow) * lda + gcol + ko0;
  const unsigned short* Bg = Bt + (size_t)(bn * 128 + grow) * ldb + gcol + ko0;
  unsigned short* Asl = As + wave * 2048;
  unsigned short* Bsl = Bs + wave * 2048;

  f32x4 acc[4][4];
#pragma unroll
  for (int i = 0; i < 4; ++i)
#pragma unroll
    for (int j = 0; j < 4; ++j)
      acc[i][j] = (f32x4){0.f, 0.f, 0.f, 0.f};

  for (int ko = 0; ko < Klen; ko += 64) {
    __syncthreads();   // previous iter's compute done before overwrite
#pragma unroll
    for (int i = 0; i < 4; ++i) {
      __builtin_amdgcn_global_load_lds(
          (const __attribute__((address_space(1))) void*)(Ag + (size_t)(8 * i) * lda + ko),
          (__attribute__((address_space(3))) void*)(Asl + i * 512), 16, 0, 0);
      __builtin_amdgcn_global_load_lds(
          (const __attribute__((address_space(1))) void*)(Bg + (size_t)(8 * i) * ldb + ko),
          (__attribute__((address_space(3))) void*)(Bsl + i * 512), 16, 0, 0);
    }
    __syncthreads();   // s_waitcnt vmcnt(0) + barrier

#pragma unroll
    for (int kk = 0; kk < 2; ++kk) {
      short8 av[4], bv[4];
#pragma unroll
      for (int mt = 0; mt < 4; ++mt) {
        const int r = wy * 64 + mt * 16 + lm;
        av[mt] = *(const short8*)(As + r * 64 + (((kk * 4 + quad) ^ (lm & 7)) << 3));
      }
#pragma unroll
      for (int nt = 0; nt < 4; ++nt) {
        const int r = wx * 64 + nt * 16 + lm;
        bv[nt] = *(const short8*)(Bs + r * 64 + (((kk * 4 + quad) ^ (lm & 7)) << 3));
      }
#pragma unroll
      for (int mt = 0; mt < 4; ++mt)
#pragma unroll
        for (int nt = 0; nt < 4; ++nt)
          acc[mt][nt] = __builtin_amdgcn_mfma_f32_16x16x32_bf16(
              av[mt], bv[nt], acc[mt][nt], 0, 0, 0);
    }
  }

  // epilogue: C/D layout col = lane&15, row = quad*4 + reg  [m89-verified]
  if (WMODE == 1) {
    unsigned short* C = (unsigned short*)Cv;
#pragma unroll
    for (int mt = 0; mt < 4; ++mt) {
      const int row0 = bm * 128 + wy * 64 + mt * 16 + quad * 4;
#pragma unroll
      for (int nt = 0; nt < 4; ++nt) {
        const int col = bn * 128 + wx * 64 + nt * 16 + lm;
#pragma unroll
        for (int r = 0; r < 4; ++r) {
          float v = acc[mt][nt][r];
          v = v > 0.f ? v : 0.f;
          C[(size_t)(row0 + r) * ldc + col] = f2bf(v);
        }
      }
    }
  } else if (WMODE == 0) {
    float* C = (float*)Cv;
#pragma unroll
    for (int mt = 0; mt < 4; ++mt) {
      const int row0 = bm * 128 + wy * 64 + mt * 16 + quad * 4;
#pragma unroll
      for (int nt = 0; nt < 4; ++nt) {
        const int col = bn * 128 + wx * 64 + nt * 16 + lm;
#pragma unroll
        for (int r = 0; r < 4; ++r)
          C[(size_t)(row0 + r) * ldc + col] = acc[mt][nt][r];
      }
    }
  } else {
    float* C = (float*)Cv;
#pragma unroll
    for (int mt = 0; mt < 4; ++mt) {
      const int row0 = bm * 128 + wy * 64 + mt * 16 + quad * 4;
#pragma unroll
      for (int nt = 0; nt < 4; ++nt) {
        const int col = bn * 128 + wx * 64 + nt * 16 + lm;
#pragma unroll
        for (int r = 0; r < 4; ++r)
          atomicAdd(&C[(size_t)(row0 + r) * ldc + col], acc[mt][nt][r]);
      }
    }
  }
}

// ---------------------------------------------------------------------------
// kernel_launch
// inputs: d_in[0]=x (4096x2048 f32), d_in[1]=weights (7168x7168 f32),
//         d_in[2]=structure_mask (unused — mask is 1 over every slice we read)
// out: 4096x1024 f32
// ws layout: A2 bf16 4096x6144 | Bt1 bf16 4096x2048 | Bt2 bf16 1024x6144
// ---------------------------------------------------------------------------
extern "C" void kernel_launch(void* const* d_in, const int* in_sizes, int n_in,
                              void* d_out, int out_size, void* d_ws, size_t ws_size,
                              hipStream_t stream) {
  const float* x = (const float*)d_in[0];
  const float* W = (const float*)d_in[1];

  char* ws = (char*)d_ws;
  const size_t A2_BYTES  = (size_t)BATCH * LDA2 * 2;       // 50,331,648
  const size_t BT1_BYTES = (size_t)N_HID * N_IN * 2;       // 16,777,216
  unsigned short* A2  = (unsigned short*)ws;
  unsigned short* Bt1 = (unsigned short*)(ws + A2_BYTES);
  unsigned short* Bt2 = (unsigned short*)(ws + A2_BYTES + BT1_BYTES);

  // 0) zero d_out for the split-K atomic accumulation (overlaps with convs)
  hipMemsetAsync(d_out, 0, (size_t)out_size * sizeof(float), stream);

  // 1) x -> bf16 into A2[:, 0:2048]
  conv_x_kernel<<<(BATCH * N_IN / 4) / 256, 256, 0, stream>>>(x, A2);

  // 2) Bt1[n][k] = W[k][2048+n], k<2048, n<4096  (W1^T)
  conv_t_kernel<<<dim3(N_HID / 32, N_IN / 32), 256, 0, stream>>>(
      W + N_IN, N_TOT, Bt1, N_IN, N_IN, N_HID);

  // 3) Bt2[n][k] = W[k][6144+n], k<6144, n<1024  ([W2;W3]^T)
  conv_t_kernel<<<dim3(N_OUT / 32, LDA2 / 32), 256, 0, stream>>>(
      W + N_IN + N_HID, N_TOT, Bt2, LDA2, LDA2, N_OUT);

  // 4) H = relu(x @ W1) -> bf16 into A2[:, 2048:6144]
  gemm_bt<1><<<dim3(N_HID / 128, BATCH / 128), 256, 0, stream>>>(
      A2, LDA2, Bt1, N_IN, A2 + N_IN, LDA2, N_IN);

  // 5) out = [x,H] @ [W2;W3] -> fp32 d_out, split-K=2 via atomicAdd
  gemm_bt<2><<<dim3(N_OUT / 128, BATCH / 128, 2), 256, 0, stream>>>(
      A2, LDA2, Bt2, LDA2, d_out, N_OUT, LDA2 / 2);
}